// Round 5
// baseline (316.674 us; speedup 1.0000x reference)
//
#include <hip/hip_runtime.h>

// Layout: [b=1, nface=8, ns=8, ns=8, H=258, W=258, c=1] fp32
// => 512 slabs of 258x258. Flat index f = slab*66564 + h*258 + w.
//
// Reference semantics (all RHS read ORIGINAL x; W-axis assigns done last, so
// they win at corners):
//   w==0   -> src = x[h, 1]    = f + 1
//   w==257 -> src = x[h, 256]  = f - 1
//   h==0   -> src = x[1, w]    = f + 258   (only if w not 0/257)
//   h==257 -> src = x[256, w]  = f - 258   (only if w not 0/257)
//   else   -> src = x[h, w]    = f
// out[f] = x[src] * halo[f]

static constexpr int W_DIM = 258;
static constexpr int HW    = 258 * 258;        // 66564
static constexpr int N_ELEM = 512 * HW;        // 34,080,768 (divisible by 4)
static constexpr int N4    = N_ELEM / 4;       // 8,520,192

__global__ void __launch_bounds__(256) halo_mul_kernel(
    const float* __restrict__ x,
    const float* __restrict__ hm,
    float* __restrict__ out)
{
    int stride = gridDim.x * blockDim.x;
    for (int i4 = blockIdx.x * blockDim.x + threadIdx.x; i4 < N4; i4 += stride) {
        const int f = i4 * 4;
        const float4 hv = reinterpret_cast<const float4*>(hm)[i4];

        const int local = f % HW;
        const int h = local / W_DIM;
        const int w = local - h * W_DIM;

        float4 xv;
        // Fast path: all 4 elements interior and within one row:
        // w..w+3 in [1,256] and h in [1,256]. (w<=253 also guarantees no row crossing.)
        if (w >= 1 && w <= 253 && h >= 1 && h <= 256) {
            xv = reinterpret_cast<const float4*>(x)[i4];
        } else {
            float vals[4];
            #pragma unroll
            for (int e = 0; e < 4; ++e) {
                const int fe = f + e;
                const int le = fe % HW;
                const int he = le / W_DIM;
                const int we = le - he * W_DIM;
                int off = 0;
                if (we == 0)              off = 1;
                else if (we == W_DIM - 1) off = -1;
                else if (he == 0)         off = W_DIM;
                else if (he == W_DIM - 1) off = -W_DIM;
                vals[e] = x[fe + off];
            }
            xv = make_float4(vals[0], vals[1], vals[2], vals[3]);
        }

        float4 ov;
        ov.x = xv.x * hv.x;
        ov.y = xv.y * hv.y;
        ov.z = xv.z * hv.z;
        ov.w = xv.w * hv.w;
        reinterpret_cast<float4*>(out)[i4] = ov;
    }
}

extern "C" void kernel_launch(void* const* d_in, const int* in_sizes, int n_in,
                              void* d_out, int out_size, void* d_ws, size_t ws_size,
                              hipStream_t stream) {
    const float* x  = reinterpret_cast<const float*>(d_in[0]);
    const float* hm = reinterpret_cast<const float*>(d_in[1]);
    float* out      = reinterpret_cast<float*>(d_out);

    // Memory-bound: cap grid at ~2048 blocks, grid-stride the rest (G11).
    const int block = 256;
    int grid = (N4 + block - 1) / block;
    if (grid > 2048) grid = 2048;
    halo_mul_kernel<<<grid, block, 0, stream>>>(x, hm, out);
}